// Round 1
// baseline (518.746 us; speedup 1.0000x reference)
//
#include <hip/hip_runtime.h>
#include <hip/hip_bf16.h>
#include <cstddef>

#define B_SZ 1024
#define C_SZ 1000
#define H_SZ 768
#define K_SZ 128

typedef __attribute__((ext_vector_type(8))) short bf16x8;
typedef __attribute__((ext_vector_type(4))) float f32x4;

// ws layout (bytes):
//   [0, 3145728) : x1 fp32 [B][H]
// (negx / Wb intermediates eliminated — conversion fused into GEMM staging)

__device__ __forceinline__ ushort bfc(float f) {
    return __bfloat16_as_ushort(__float2bfloat16(f));
}

// ---------------------------------------------------------------------------
// Kernel 1: x1 = tanh(relu(-x) @ W^T + bias) via mfma_f32_16x16x32_bf16
// 64x64 tile, BK=32, 256 threads = 2x2 waves, each wave 2x2 16x16 frags.
// fp32 -> bf16 conversion fused into the staging step; next-tile global
// loads issued between the barriers so they overlap the MFMAs.
// A-frag: lane holds A[m=lane&15][k=(lane>>4)*8 + j]
// B-frag: lane holds B[k][n=lane&15] = W[n][k]
// C/D:    col = lane&15, row = (lane>>4)*4 + reg   [verified layout]
// ---------------------------------------------------------------------------
__global__ __launch_bounds__(256) void mfma_gemm_tanh(
    const float* __restrict__ X, const float* __restrict__ W,
    const float* __restrict__ bias, float* __restrict__ x1)
{
    const int LDA = 40;                 // 32 bf16 + 8 pad = 80 B row stride
    __shared__ ushort sA[64 * LDA];
    __shared__ ushort sB[64 * LDA];

    const int t    = threadIdx.x;
    const int wave = t >> 6;            // 0..3
    const int lane = t & 63;
    const int wm   = wave >> 1;         // wave row quadrant
    const int wn   = wave & 1;          // wave col quadrant
    const int m0   = blockIdx.y * 64;
    const int n0   = blockIdx.x * 64;

    const int lr = t >> 2;              // staging row 0..63
    const int lc = (t & 3) * 8;         // staging col (elems) 0,8,16,24

    const float* __restrict__ xrow = X + (size_t)(m0 + lr) * H_SZ + lc;
    const float* __restrict__ wrow = W + (size_t)(n0 + lr) * H_SZ + lc;
    ushort* sa = &sA[lr * LDA + lc];
    ushort* sb = &sB[lr * LDA + lc];

    f32x4 acc[2][2] = {};

    const int fr = lane & 15;           // fragment row within 16x16
    const int fk = (lane >> 4) * 8;     // fragment k offset 0,8,16,24

    // prologue loads (k0 = 0)
    float4 a0 = *(const float4*)(xrow);
    float4 a1 = *(const float4*)(xrow + 4);
    float4 b0 = *(const float4*)(wrow);
    float4 b1 = *(const float4*)(wrow + 4);

    for (int k0 = 0; k0 < H_SZ; k0 += 32) {
        // convert current tile (negx = relu(-x) folded in) and stage to LDS
        union { ushort u[8]; bf16x8 v; } pa, pb;
        pa.u[0] = bfc(fmaxf(-a0.x, 0.f)); pa.u[1] = bfc(fmaxf(-a0.y, 0.f));
        pa.u[2] = bfc(fmaxf(-a0.z, 0.f)); pa.u[3] = bfc(fmaxf(-a0.w, 0.f));
        pa.u[4] = bfc(fmaxf(-a1.x, 0.f)); pa.u[5] = bfc(fmaxf(-a1.y, 0.f));
        pa.u[6] = bfc(fmaxf(-a1.z, 0.f)); pa.u[7] = bfc(fmaxf(-a1.w, 0.f));
        pb.u[0] = bfc(b0.x); pb.u[1] = bfc(b0.y);
        pb.u[2] = bfc(b0.z); pb.u[3] = bfc(b0.w);
        pb.u[4] = bfc(b1.x); pb.u[5] = bfc(b1.y);
        pb.u[6] = bfc(b1.z); pb.u[7] = bfc(b1.w);
        *(bf16x8*)sa = pa.v;
        *(bf16x8*)sb = pb.v;
        __syncthreads();

        // issue next-tile global loads so they overlap the MFMAs below
        if (k0 + 32 < H_SZ) {
            a0 = *(const float4*)(xrow + k0 + 32);
            a1 = *(const float4*)(xrow + k0 + 36);
            b0 = *(const float4*)(wrow + k0 + 32);
            b1 = *(const float4*)(wrow + k0 + 36);
        }

        #pragma unroll
        for (int fi = 0; fi < 2; ++fi) {
            bf16x8 af = *(const bf16x8*)(&sA[(wm * 32 + fi * 16 + fr) * LDA + fk]);
            #pragma unroll
            for (int fj = 0; fj < 2; ++fj) {
                bf16x8 bf = *(const bf16x8*)(&sB[(wn * 32 + fj * 16 + fr) * LDA + fk]);
                acc[fi][fj] = __builtin_amdgcn_mfma_f32_16x16x32_bf16(
                    af, bf, acc[fi][fj], 0, 0, 0);
            }
        }
        __syncthreads();
    }

    const int col   = lane & 15;
    const int rbase = (lane >> 4) * 4;
    #pragma unroll
    for (int fi = 0; fi < 2; ++fi) {
        #pragma unroll
        for (int fj = 0; fj < 2; ++fj) {
            const int n  = n0 + wn * 32 + fj * 16 + col;
            const float bv = bias[n];
            #pragma unroll
            for (int r = 0; r < 4; ++r) {
                const int m = m0 + wm * 32 + fi * 16 + rbase + r;
                x1[(size_t)m * H_SZ + n] = tanhf(acc[fi][fj][r] + bv);
            }
        }
    }
}

// ---------------------------------------------------------------------------
// Kernel 2: logits[b][k] = sum_h x1[b][h] * CW[y[b]][h][k]
// 1 block / sample, 256 threads: k4 = t&31 (32 float4 cover K=128),
// hg = t>>5 (8 h-groups). unroll 8 -> 8 float4 loads in flight / thread.
// Single-barrier reduction: 32 lanes each sum their 8 hg partials.
// ---------------------------------------------------------------------------
__global__ __launch_bounds__(256) void gather_dot(
    const float* __restrict__ x1, const int* __restrict__ y,
    const float* __restrict__ cw, float* __restrict__ out)
{
    const int b  = blockIdx.x;
    const int t  = threadIdx.x;
    const int k4 = t & 31;
    const int hg = t >> 5;

    __shared__ float sx[H_SZ];
    __shared__ f32x4 red[256];

    const int cls = y[b];
    const f32x4* __restrict__ wrow =
        (const f32x4*)(cw + (size_t)cls * H_SZ * K_SZ);

    if (t < H_SZ / 4)
        ((f32x4*)sx)[t] = ((const f32x4*)(x1 + (size_t)b * H_SZ))[t];
    __syncthreads();

    f32x4 acc = {};
    #pragma unroll 8
    for (int h = hg; h < H_SZ; h += 8) {
        acc += wrow[h * 32 + k4] * sx[h];
    }

    red[t] = acc;
    __syncthreads();
    if (t < 32) {
        f32x4 r = red[t];
        #pragma unroll
        for (int j = 1; j < 8; ++j)
            r += red[t + 32 * j];
        ((f32x4*)out)[(size_t)b * 32 + t] = r;
    }
}

extern "C" void kernel_launch(void* const* d_in, const int* in_sizes, int n_in,
                              void* d_out, int out_size, void* d_ws, size_t ws_size,
                              hipStream_t stream) {
    const float* x    = (const float*)d_in[0];   // [B, H]
    const int*   y    = (const int*)  d_in[1];   // [B]
    const float* cw   = (const float*)d_in[2];   // [C, H, K]
    // d_in[3] = class_bias — unused by the reference math
    const float* Wlin = (const float*)d_in[4];   // [H, H]
    const float* blin = (const float*)d_in[5];   // [H]
    float* out = (float*)d_out;                  // [B, K]

    float* x1 = (float*)d_ws;

    dim3 g1(H_SZ / 64, B_SZ / 64);               // 12 x 16 = 192 blocks
    mfma_gemm_tanh<<<g1, 256, 0, stream>>>(x, Wlin, blin, x1);

    gather_dot<<<B_SZ, 256, 0, stream>>>(x1, y, cw, out);
}